// Round 13
// baseline (194.746 us; speedup 1.0000x reference)
//
#include <hip/hip_runtime.h>
#include <cmath>

#define C_DIM   1024
#define H_DIM   16
#define HD      64
#define N_TOK   2048
#define M_TOK   4096
#define LOG2E   1.44269504088896340736f

typedef _Float16 f16;
typedef __attribute__((ext_vector_type(8))) _Float16 f16x8;
typedef __attribute__((ext_vector_type(4))) _Float16 f16x4;
typedef __attribute__((ext_vector_type(2))) __fp16   fp16x2_b;  // builtin ret type
typedef __attribute__((ext_vector_type(4))) float    f32x4;

// async global->LDS, 16B per lane; LDS dest = wave-uniform base + lane*16
__device__ __forceinline__ void gl_lds16(const void* g, void* l) {
  __builtin_amdgcn_global_load_lds((const __attribute__((address_space(1))) void*)g,
                                   (__attribute__((address_space(3))) void*)l, 16, 0, 0);
}

// ---------------------------------------------------------------------------
// fp32 -> fp16 convert: x (4.19M), qkv_w (3.15M), proj_w (1.05M), float4/thread
// ---------------------------------------------------------------------------
#define CVT_X4 1048576
#define CVT_W4 786432
#define CVT_P4 262144
__global__ __launch_bounds__(256) void cvt_all(const float* __restrict__ x,
                                               const float* __restrict__ w1,
                                               const float* __restrict__ w2,
                                               f16* __restrict__ xh,
                                               f16* __restrict__ wh1,
                                               f16* __restrict__ wh2) {
  const int i = blockIdx.x * 256 + threadIdx.x;
  const float4* src; f16* dst; int off;
  if (i < CVT_X4)               { src = (const float4*)x;  dst = xh;  off = i; }
  else if (i < CVT_X4 + CVT_W4) { src = (const float4*)w1; dst = wh1; off = i - CVT_X4; }
  else                          { src = (const float4*)w2; dst = wh2; off = i - CVT_X4 - CVT_W4; }
  const float4 v = src[off];
  union { f16 h[4]; ushort4 u; } p;
  p.h[0] = (f16)v.x; p.h[1] = (f16)v.y; p.h[2] = (f16)v.z; p.h[3] = (f16)v.w;
  *(ushort4*)(dst + (size_t)off * 4) = p.u;
}

#define SUB  (128 * 32)  // halves per BK=32 128-row sub-tile buffer
#define SUBB (64 * 32)   // halves per BK=32 64-row sub-tile buffer (proj B)
#define SA_Q (256 * 32)  // halves per BK=32 256-row A buffer (qkv)
#define SB_Q (128 * 32)  // halves per BK=32 128-row B buffer (qkv)

// ---------------------------------------------------------------------------
// QKV GEMM (unchanged, v13): 256x128 tile, 8 waves (4Mx2N), 2-phase BK=32,
// XCD-swizzled grid (384 blocks). Fused epilogue: q -> L2-norm -> qb;
// k -> L2-norm*0.125*log2e*s -> kb; v -> vfrag packed for K=32 PV B-frags.
// ---------------------------------------------------------------------------
__global__ __launch_bounds__(512) void gemm_qkv(const f16* __restrict__ A,
                                                const f16* __restrict__ B,
                                                const float* __restrict__ score,
                                                f16* __restrict__ qb,
                                                f16* __restrict__ kb,
                                                f16* __restrict__ vfrag) {
  __shared__ __align__(16) struct { f16 As[2 * SA_Q]; f16 Bs[2 * SB_Q]; } sm;
  f32x4 acc[4][4];
#pragma unroll
  for (int i = 0; i < 4; ++i)
#pragma unroll
    for (int j = 0; j < 4; ++j) acc[i][j] = (f32x4){0.f, 0.f, 0.f, 0.f};

  // XCD swizzle: grid (24,16), nwg=384 (384%8==0 -> bijective).
  const int ld  = blockIdx.y * 24 + blockIdx.x;
  const int xcd = ld & 7, idx = ld >> 3;          // idx 0..47
  const int byn = xcd * 2 + idx / 24;             // 0..15
  const int bxn = idx % 24;                       // 0..23
  const int bm = byn * 256, bn = bxn * 128;

  const int tid  = threadIdx.x;
  const int w    = tid >> 6, lane = tid & 63;     // w 0..7
  const int wm   = w >> 1,   wn   = w & 1;        // wave tile 64x64 at (wm,wn)
  const int ln   = lane & 15, quad = lane >> 4;
  const int sr   = lane >> 2;                                  // row in 16-row chunk
  const int sc   = (((lane & 3) ^ ((lane >> 4) & 3)) << 3);    // swizzled k-chunk (halves)
  const int ro   = ((quad ^ ((ln >> 2) & 3)) << 3);            // matching read swizzle

  const f16* Ag0 = A + (size_t)(bm + w * 16 + sr) * C_DIM + sc;        // rows 0..127
  const f16* Ag1 = A + (size_t)(bm + (w + 8) * 16 + sr) * C_DIM + sc;  // rows 128..255
  const f16* Bg0 = B + (size_t)(bn + w * 16 + sr) * C_DIM + sc;        // rows 0..127
  f16* Al0 = sm.As + (w * 16) * 32;
  f16* Al1 = sm.As + ((w + 8) * 16) * 32;
  f16* Bl0 = sm.Bs + (w * 16) * 32;

  // ---- prologue: stage k=0 into buffer 0 ----
  gl_lds16(Ag0, Al0);
  gl_lds16(Ag1, Al1);
  gl_lds16(Bg0, Bl0);
  __syncthreads();

  int cur = 0;
  for (int k0 = 0; k0 < C_DIM; k0 += 32) {
    const int nxt = cur ^ 1;
    if (k0 + 32 < C_DIM) {
      gl_lds16(Ag0 + k0 + 32, Al0 + nxt * SA_Q);
      gl_lds16(Ag1 + k0 + 32, Al1 + nxt * SA_Q);
      gl_lds16(Bg0 + k0 + 32, Bl0 + nxt * SB_Q);
    }
    const f16* Asub = sm.As + cur * SA_Q;
    const f16* Bsub = sm.Bs + cur * SB_Q;
    f16x8 af[4], bf[4];
#pragma unroll
    for (int fm = 0; fm < 4; ++fm)
      af[fm] = *(const f16x8*)&Asub[(wm * 64 + fm * 16 + ln) * 32 + ro];
#pragma unroll
    for (int fn = 0; fn < 4; ++fn)
      bf[fn] = *(const f16x8*)&Bsub[(wn * 64 + fn * 16 + ln) * 32 + ro];
#pragma unroll
    for (int fm = 0; fm < 4; ++fm)
#pragma unroll
      for (int fn = 0; fn < 4; ++fn)
        acc[fm][fn] = __builtin_amdgcn_mfma_f32_16x16x32_f16(af[fm], bf[fn], acc[fm][fn], 0, 0, 0);
    __syncthreads();
    cur = nxt;
  }

  // ---- fused epilogue ----
  const int col0 = bn + wn * 64;
  const int mode = col0 >> 10;
  const int h    = (col0 >> 6) & 15;

  if (mode <= 1) {
    f16* dst = mode ? kb : qb;
#pragma unroll
    for (int fm = 0; fm < 4; ++fm) {
#pragma unroll
      for (int r = 0; r < 4; ++r) {
        const int m = bm + wm * 64 + fm * 16 + quad * 4 + r;
        const int b = m >> 11, n = m & (N_TOK - 1);
        float ss = acc[fm][0][r] * acc[fm][0][r] + acc[fm][1][r] * acc[fm][1][r]
                 + acc[fm][2][r] * acc[fm][2][r] + acc[fm][3][r] * acc[fm][3][r];
        ss += __shfl_xor(ss, 1, 64);
        ss += __shfl_xor(ss, 2, 64);
        ss += __shfl_xor(ss, 4, 64);
        ss += __shfl_xor(ss, 8, 64);
        float sc2 = 1.0f / (sqrtf(ss) + 1e-8f);
        if (mode) sc2 *= 0.125f * LOG2E * score[n];
        f16* drow = dst + (((size_t)(b * H_DIM + h) * N_TOK + n) << 6);
#pragma unroll
        for (int fn = 0; fn < 4; ++fn)
          drow[fn * 16 + ln] = (f16)(acc[fm][fn][r] * sc2);
      }
    }
  } else {
    // V packing for K=32 PV: group32 = two fm's; half j<4 from fm=2F (r=j),
    // half j>=4 from fm=2F+1 (r=j-4). col = dblk*16+ln.
    const int m0  = bm + wm * 64;
    const int b   = m0 >> 11;
    const int tg0 = (m0 & (N_TOK - 1)) >> 5;      // 32-token group index
    f16* vb = vfrag + (((size_t)(b * H_DIM + h) * 64 + tg0) * 4) * 512 + lane * 8;
#pragma unroll
    for (int F = 0; F < 2; ++F)
#pragma unroll
      for (int dblk = 0; dblk < 4; ++dblk) {
        f16x8 v8;
#pragma unroll
        for (int r = 0; r < 4; ++r) v8[r]     = (f16)acc[2 * F][dblk][r];
#pragma unroll
        for (int r = 0; r < 4; ++r) v8[4 + r] = (f16)acc[2 * F + 1][dblk][r];
        *(f16x8*)(vb + ((size_t)F * 4 + dblk) * 512) = v8;
      }
  }
}

// ---------------------------------------------------------------------------
// Proj GEMM (unchanged): 128x64 tile, 4 waves (4x1), acc[2][4]. Grid (16,32)
// = 512 blocks = 2/CU. XCD-swizzled. 24KB LDS, 2-phase BK=32 schedule.
// ---------------------------------------------------------------------------
__global__ __launch_bounds__(256) void gemm_proj(const f16* __restrict__ A,
                                                 const f16* __restrict__ B,
                                                 const float* __restrict__ bias,
                                                 float* __restrict__ out) {
  __shared__ __align__(16) struct { f16 As[2 * SUB]; f16 Bs[2 * SUBB]; } sm;
  f32x4 acc[2][4];
#pragma unroll
  for (int i = 0; i < 2; ++i)
#pragma unroll
    for (int j = 0; j < 4; ++j) acc[i][j] = (f32x4){0.f, 0.f, 0.f, 0.f};

  // XCD swizzle: grid (16,32), nwg=512 (512%8==0 -> bijective).
  const int ld  = blockIdx.y * 16 + blockIdx.x;
  const int xcd = ld & 7, idx = ld >> 3;          // idx 0..63
  const int byn = xcd * 4 + idx / 16;             // 0..31
  const int bxn = idx % 16;                       // 0..15
  const int bm = byn * 128, bn = bxn * 64;

  const int tid  = threadIdx.x;
  const int w    = tid >> 6, lane = tid & 63;
  const int ln   = lane & 15, quad = lane >> 4;
  const int sr   = lane >> 2;
  const int sc   = (((lane & 3) ^ ((lane >> 4) & 3)) << 3);
  const int ro   = ((quad ^ ((ln >> 2) & 3)) << 3);

  const f16* Ag0 = A + (size_t)(bm + w * 16 + sr) * C_DIM + sc;
  const f16* Ag1 = A + (size_t)(bm + (w + 4) * 16 + sr) * C_DIM + sc;
  const f16* Bg0 = B + (size_t)(bn + w * 16 + sr) * C_DIM + sc;
  f16* Al0 = sm.As + (w * 16) * 32;
  f16* Al1 = sm.As + ((w + 4) * 16) * 32;
  f16* Bl0 = sm.Bs + (w * 16) * 32;

  // ---- prologue ----
  gl_lds16(Ag0, Al0);
  gl_lds16(Ag1, Al1);
  gl_lds16(Bg0, Bl0);
  __syncthreads();

  int cur = 0;
  for (int k0 = 0; k0 < C_DIM; k0 += 32) {
    const int nxt = cur ^ 1;
    if (k0 + 32 < C_DIM) {
      gl_lds16(Ag0 + k0 + 32, Al0 + nxt * SUB);
      gl_lds16(Ag1 + k0 + 32, Al1 + nxt * SUB);
      gl_lds16(Bg0 + k0 + 32, Bl0 + nxt * SUBB);
    }
    const f16* Asub = sm.As + cur * SUB;
    const f16* Bsub = sm.Bs + cur * SUBB;
    f16x8 af[2], bf[4];
#pragma unroll
    for (int fm = 0; fm < 2; ++fm)
      af[fm] = *(const f16x8*)&Asub[(w * 32 + fm * 16 + ln) * 32 + ro];
#pragma unroll
    for (int fn = 0; fn < 4; ++fn)
      bf[fn] = *(const f16x8*)&Bsub[(fn * 16 + ln) * 32 + ro];
#pragma unroll
    for (int fm = 0; fm < 2; ++fm)
#pragma unroll
      for (int fn = 0; fn < 4; ++fn)
        acc[fm][fn] = __builtin_amdgcn_mfma_f32_16x16x32_f16(af[fm], bf[fn], acc[fm][fn], 0, 0, 0);
    __syncthreads();
    cur = nxt;
  }

  // ---- epilogue ----
  float bv[4];
#pragma unroll
  for (int fn = 0; fn < 4; ++fn) bv[fn] = bias[bn + fn * 16 + ln];
#pragma unroll
  for (int fm = 0; fm < 2; ++fm)
#pragma unroll
    for (int r = 0; r < 4; ++r) {
      const int m = bm + w * 32 + fm * 16 + quad * 4 + r;
#pragma unroll
      for (int fn = 0; fn < 4; ++fn)
        out[(size_t)m * C_DIM + bn + fn * 16 + ln] = acc[fm][fn][r] + bv[fn];
    }
}

// ---------------------------------------------------------------------------
// MFMA attention v14 = v13 + 3-buffer V with 2-ahead DMA and counted drain:
// V DMA issued 2 tiles ahead into Vl[(t+2)%3]; barrier is raw s_barrier with
// explicit s_waitcnt vmcnt(1) lgkmcnt(0) — own DMA(t+1) proven complete by
// wave-FIFO (K-reg prefetch load issued after it is drained at the K-store);
// the 2-ahead DMA stays in flight ACROSS the barrier (2 bodies of latency
// slack vs 1 under __syncthreads' vmcnt(0)). Buffer (t+2)%3 was last read at
// body t-1, a barrier earlier -> WAR-safe. Final vmcnt(0) before epilogue.
// LDS 40KB, still 2 blocks/CU (grid-capped). Compute path identical to v13.
// ---------------------------------------------------------------------------
__global__ __launch_bounds__(512) void attn_mfma(const f16* __restrict__ qb,
                                                 const f16* __restrict__ kb,
                                                 const f16* __restrict__ vfrag,
                                                 const float* __restrict__ score,
                                                 const int* __restrict__ usem,
                                                 f16* __restrict__ obuf) {
  __shared__ __align__(16) f16 Kl[2][64][64];
  __shared__ __align__(16) f16 Vl[3][4096];

  const int tid  = threadIdx.x;
  const int w    = tid >> 6;           // 0..7
  const int lane = tid & 63;
  const int ln   = lane & 15;
  const int quad = lane >> 4;
  const int bh = blockIdx.x;                 // XCD-pinned: bh%8
  const int q0 = blockIdx.y * 128;
  const int b  = bh >> 4, h = bh & 15;
  const int umask = *usem;

  // Q B-frags: 16 q rows per wave (8 waves = 128 rows), in registers
  const f16* qp = qb + ((size_t)bh * N_TOK + q0 + w * 16 + ln) * HD + quad * 8;
  const f16x8 bq0 = *(const f16x8*)(qp);
  const f16x8 bq1 = *(const f16x8*)(qp + 32);
  const float sq = score[q0 + w * 16 + ln] - 0.1f;

  f32x4 O[4], Ol;
#pragma unroll
  for (int t = 0; t < 4; ++t) O[t] = (f32x4){0.f, 0.f, 0.f, 0.f};
  Ol = (f32x4){0.f, 0.f, 0.f, 0.f};
  const f16x8 ones8 = (f16x8){(f16)1.f, (f16)1.f, (f16)1.f, (f16)1.f,
                              (f16)1.f, (f16)1.f, (f16)1.f, (f16)1.f};

  const int sr  = tid >> 3;            // K stage row 0..63
  const int scc = (tid & 7) << 3;      // K stage col (halves, 16B per thread)
  const int sw  = (sr & 7) << 3;       // write-side swizzle (halves)
  const int wc0 = scc ^ sw;            // swizzled store col
  const int e3  = (ln & 7) << 3;       // read-side swizzle (halves)
  const int rc0 = (quad * 8) ^ e3;     // swizzled read cols
  const int rc1 = (32 + quad * 8) ^ e3;
  const int c0  = w;                   // V DMA chunk for this wave (1 of 8)
  const f16* kg = kb    + (size_t)bh * N_TOK * HD;
  const f16* vg = vfrag + (size_t)bh * 128 * 1024;

  // ---- prologue: V tiles 0,1 -> Vl[0],Vl[1]; K tile 0 -> Kl[0] ----
  gl_lds16(vg + (size_t)0 * 4096 + c0 * 512 + lane * 8, &Vl[0][c0 * 512]);
  gl_lds16(vg + (size_t)1 * 4096 + c0 * 512 + lane * 8, &Vl[1][c0 * 512]);
  {
    const float4 k0r = *(const float4*)(kg + (size_t)sr * HD + scc);
    *(float4*)&Kl[0][sr][wc0] = k0r;
  }
  __syncthreads();

  int cur2 = 0, cur3 = 0;
  for (int t = 0; t < 32; ++t) {
    // ---- K regs for tile t+1 (issued first), V DMA for tile t+2 ----
    const int kn  = ((t + 1) & 31) * 64;
    const float4 kn0 = *(const float4*)(kg + (size_t)(kn + sr) * HD + scc);
    const int tp2 = (t + 2) & 31;
    const int b3  = (cur3 + 2 >= 3) ? cur3 - 1 : cur3 + 2;   // (t+2)%3
    gl_lds16(vg + (size_t)tp2 * 4096 + c0 * 512 + lane * 8, &Vl[b3][c0 * 512]);

    // ---- S^T = K.Q^T from Kl[cur2] (swizzled reads) ----
    f16x4 af[4];
    f32x4 c[4];
    __builtin_amdgcn_s_setprio(1);
#pragma unroll
    for (int tt = 0; tt < 4; ++tt) {
      const f16x8 ka0 = *(const f16x8*)&Kl[cur2][tt * 16 + ln][rc0];
      const f16x8 ka1 = *(const f16x8*)&Kl[cur2][tt * 16 + ln][rc1];
      f32x4 cc = (f32x4){0.f, 0.f, 0.f, 0.f};
      cc = __builtin_amdgcn_mfma_f32_16x16x32_f16(ka0, bq0, cc, 0, 0, 0);
      cc = __builtin_amdgcn_mfma_f32_16x16x32_f16(ka1, bq1, cc, 0, 0, 0);
      c[tt] = cc;
    }
    __builtin_amdgcn_s_setprio(0);

    // ---- softmax in-register (log2 domain; masked -> exp2(0)=1) ----
    const int k0 = t * 64;
#pragma unroll
    for (int tt = 0; tt < 4; ++tt) {
      const float4 sk = *(const float4*)&score[k0 + tt * 16 + quad * 4];
      const float skr[4] = {sk.x, sk.y, sk.z, sk.w};
      float e[4];
#pragma unroll
      for (int r = 0; r < 4; ++r) {
        float x = c[tt][r];
        if (umask && !(skr[r] > sq)) x = 0.f;
        e[r] = __builtin_amdgcn_exp2f(x);
      }
      union { fp16x2_b p[2]; f16x4 v; } u;
      u.p[0] = __builtin_amdgcn_cvt_pkrtz(e[0], e[1]);
      u.p[1] = __builtin_amdgcn_cvt_pkrtz(e[2], e[3]);
      af[tt] = u.v;
    }

    // ---- O += P V at K=32 from Vl[cur3]; V pre-packed by gemm_qkv ----
    const f16* Vq = &Vl[cur3][0];
    __builtin_amdgcn_s_setprio(1);
#pragma unroll
    for (int t32 = 0; t32 < 2; ++t32) {
      const f16x8 a8 = __builtin_shufflevector(af[2 * t32], af[2 * t32 + 1],
                                               0, 1, 2, 3, 4, 5, 6, 7);
      Ol = __builtin_amdgcn_mfma_f32_16x16x32_f16(a8, ones8, Ol, 0, 0, 0);
#pragma unroll
      for (int dblk = 0; dblk < 4; ++dblk) {
        const f16x8 vv = *(const f16x8*)&Vq[(t32 * 4 + dblk) * 512 + lane * 8];
        O[dblk] = __builtin_amdgcn_mfma_f32_16x16x32_f16(a8, vv, O[dblk], 0, 0, 0);
      }
    }
    __builtin_amdgcn_s_setprio(0);

    // ---- stage prefetched K into Kl[cur2^1]; counted-drain barrier ----
    *(float4*)&Kl[cur2 ^ 1][sr][wc0] = kn0;
    asm volatile("s_waitcnt vmcnt(1) lgkmcnt(0)" ::: "memory");
    __builtin_amdgcn_s_barrier();
    __builtin_amdgcn_sched_barrier(0);

    cur2 ^= 1;
    cur3 = (cur3 == 2) ? 0 : cur3 + 1;
  }
  // drain remaining in-flight LDS-DMA before workgroup teardown
  asm volatile("s_waitcnt vmcnt(0)" ::: "memory");

  // ---- epilogue: l for q=quad*4+r sits in Ol[r] on every lane ----
#pragma unroll
  for (int r = 0; r < 4; ++r) {
    const float inv = 1.0f / Ol[r];
    const size_t row = (size_t)(b * N_TOK + q0 + w * 16 + quad * 4 + r);
#pragma unroll
    for (int t2 = 0; t2 < 4; ++t2)
      obuf[row * C_DIM + h * HD + t2 * 16 + ln] = (f16)(O[t2][r] * inv);
  }
}

// ---------------------------------------------------------------------------
extern "C" void kernel_launch(void* const* d_in, const int* in_sizes, int n_in,
                              void* d_out, int out_size, void* d_ws, size_t ws_size,
                              hipStream_t stream) {
  const float* x      = (const float*)d_in[0];
  const float* score  = (const float*)d_in[1];
  const float* qkv_w  = (const float*)d_in[2];
  const float* proj_w = (const float*)d_in[3];
  const float* proj_b = (const float*)d_in[4];
  const int*   usem   = (const int*)d_in[5];
  float* out = (float*)d_out;

  f16* xh    = (f16*)d_ws;
  f16* wh    = xh  + (size_t)M_TOK * C_DIM;
  f16* pwh   = wh  + (size_t)3 * C_DIM * C_DIM;
  f16* qb    = pwh + (size_t)C_DIM * C_DIM;
  f16* kb    = qb  + (size_t)M_TOK * C_DIM;
  f16* vfrag = kb  + (size_t)M_TOK * C_DIM;
  f16* obuf  = vfrag + (size_t)M_TOK * C_DIM;

  cvt_all<<<(CVT_X4 + CVT_W4 + CVT_P4) / 256, 256, 0, stream>>>(x, qkv_w, proj_w, xh, wh, pwh);
  {
    dim3 grid(3 * C_DIM / 128, M_TOK / 256);   // 24 x 16 = 384 blocks, 512 thr
    gemm_qkv<<<grid, 512, 0, stream>>>(xh, wh, score, qb, kb, vfrag);
  }
  {
    dim3 grid(2 * H_DIM, N_TOK / 128);   // bh fastest -> XCD-pinned K/V
    attn_mfma<<<grid, 512, 0, stream>>>(qb, kb, vfrag, score, usem, obuf);
  }
  {
    dim3 grid(C_DIM / 64, M_TOK / 128);  // 512 blocks = 2/CU
    gemm_proj<<<grid, 256, 0, stream>>>(obuf, pwh, proj_b, out);
  }
}

// Round 14
// 187.405 us; speedup vs baseline: 1.0392x; 1.0392x over previous
//
#include <hip/hip_runtime.h>
#include <cmath>

#define C_DIM   1024
#define H_DIM   16
#define HD      64
#define N_TOK   2048
#define M_TOK   4096
#define LOG2E   1.44269504088896340736f

typedef _Float16 f16;
typedef __attribute__((ext_vector_type(8))) _Float16 f16x8;
typedef __attribute__((ext_vector_type(4))) _Float16 f16x4;
typedef __attribute__((ext_vector_type(2))) __fp16   fp16x2_b;  // builtin ret type
typedef __attribute__((ext_vector_type(4))) float    f32x4;

// async global->LDS, 16B per lane; LDS dest = wave-uniform base + lane*16
__device__ __forceinline__ void gl_lds16(const void* g, void* l) {
  __builtin_amdgcn_global_load_lds((const __attribute__((address_space(1))) void*)g,
                                   (__attribute__((address_space(3))) void*)l, 16, 0, 0);
}

// ---------------------------------------------------------------------------
// fp32 -> fp16 convert: x (4.19M), qkv_w (3.15M), proj_w (1.05M), float4/thread
// ---------------------------------------------------------------------------
#define CVT_X4 1048576
#define CVT_W4 786432
#define CVT_P4 262144
__global__ __launch_bounds__(256) void cvt_all(const float* __restrict__ x,
                                               const float* __restrict__ w1,
                                               const float* __restrict__ w2,
                                               f16* __restrict__ xh,
                                               f16* __restrict__ wh1,
                                               f16* __restrict__ wh2) {
  const int i = blockIdx.x * 256 + threadIdx.x;
  const float4* src; f16* dst; int off;
  if (i < CVT_X4)               { src = (const float4*)x;  dst = xh;  off = i; }
  else if (i < CVT_X4 + CVT_W4) { src = (const float4*)w1; dst = wh1; off = i - CVT_X4; }
  else                          { src = (const float4*)w2; dst = wh2; off = i - CVT_X4 - CVT_W4; }
  const float4 v = src[off];
  union { f16 h[4]; ushort4 u; } p;
  p.h[0] = (f16)v.x; p.h[1] = (f16)v.y; p.h[2] = (f16)v.z; p.h[3] = (f16)v.w;
  *(ushort4*)(dst + (size_t)off * 4) = p.u;
}

#define SUB  (128 * 32)  // halves per BK=32 128-row sub-tile buffer
#define SUBB (64 * 32)   // halves per BK=32 64-row sub-tile buffer (proj B)
#define SA_Q (256 * 32)  // halves per BK=32 256-row A buffer (qkv)
#define SB_Q (128 * 32)  // halves per BK=32 128-row B buffer (qkv)

// ---------------------------------------------------------------------------
// QKV GEMM (R8 structure): 256x128 tile, 8 waves (4Mx2N), 2-phase BK=32,
// XCD-swizzled grid (384 blocks). Fused epilogue: q -> L2-norm -> qb;
// k -> L2-norm*0.125*log2e*s -> kb; v -> vfrag packed for K=32 PV B-frags:
// vfrag[((bh*64+grp32)*4+dblk)*512 + lane*8]; lane's 8 halves = tokens
// {g+quad*4+j}j<4 U {g+16+quad*4+(j-4)} at col dblk*16+ln — i.e. the concat
// of two 16x16x16-order frags, matching A=concat(af[2t],af[2t+1]).
// ---------------------------------------------------------------------------
__global__ __launch_bounds__(512) void gemm_qkv(const f16* __restrict__ A,
                                                const f16* __restrict__ B,
                                                const float* __restrict__ score,
                                                f16* __restrict__ qb,
                                                f16* __restrict__ kb,
                                                f16* __restrict__ vfrag) {
  __shared__ __align__(16) struct { f16 As[2 * SA_Q]; f16 Bs[2 * SB_Q]; } sm;
  f32x4 acc[4][4];
#pragma unroll
  for (int i = 0; i < 4; ++i)
#pragma unroll
    for (int j = 0; j < 4; ++j) acc[i][j] = (f32x4){0.f, 0.f, 0.f, 0.f};

  // XCD swizzle: grid (24,16), nwg=384 (384%8==0 -> bijective).
  const int ld  = blockIdx.y * 24 + blockIdx.x;
  const int xcd = ld & 7, idx = ld >> 3;          // idx 0..47
  const int byn = xcd * 2 + idx / 24;             // 0..15
  const int bxn = idx % 24;                       // 0..23
  const int bm = byn * 256, bn = bxn * 128;

  const int tid  = threadIdx.x;
  const int w    = tid >> 6, lane = tid & 63;     // w 0..7
  const int wm   = w >> 1,   wn   = w & 1;        // wave tile 64x64 at (wm,wn)
  const int ln   = lane & 15, quad = lane >> 4;
  const int sr   = lane >> 2;                                  // row in 16-row chunk
  const int sc   = (((lane & 3) ^ ((lane >> 4) & 3)) << 3);    // swizzled k-chunk (halves)
  const int ro   = ((quad ^ ((ln >> 2) & 3)) << 3);            // matching read swizzle

  const f16* Ag0 = A + (size_t)(bm + w * 16 + sr) * C_DIM + sc;        // rows 0..127
  const f16* Ag1 = A + (size_t)(bm + (w + 8) * 16 + sr) * C_DIM + sc;  // rows 128..255
  const f16* Bg0 = B + (size_t)(bn + w * 16 + sr) * C_DIM + sc;        // rows 0..127
  f16* Al0 = sm.As + (w * 16) * 32;
  f16* Al1 = sm.As + ((w + 8) * 16) * 32;
  f16* Bl0 = sm.Bs + (w * 16) * 32;

  // ---- prologue: stage k=0 into buffer 0 ----
  gl_lds16(Ag0, Al0);
  gl_lds16(Ag1, Al1);
  gl_lds16(Bg0, Bl0);
  __syncthreads();

  int cur = 0;
  for (int k0 = 0; k0 < C_DIM; k0 += 32) {
    const int nxt = cur ^ 1;
    if (k0 + 32 < C_DIM) {
      gl_lds16(Ag0 + k0 + 32, Al0 + nxt * SA_Q);
      gl_lds16(Ag1 + k0 + 32, Al1 + nxt * SA_Q);
      gl_lds16(Bg0 + k0 + 32, Bl0 + nxt * SB_Q);
    }
    const f16* Asub = sm.As + cur * SA_Q;
    const f16* Bsub = sm.Bs + cur * SB_Q;
    f16x8 af[4], bf[4];
#pragma unroll
    for (int fm = 0; fm < 4; ++fm)
      af[fm] = *(const f16x8*)&Asub[(wm * 64 + fm * 16 + ln) * 32 + ro];
#pragma unroll
    for (int fn = 0; fn < 4; ++fn)
      bf[fn] = *(const f16x8*)&Bsub[(wn * 64 + fn * 16 + ln) * 32 + ro];
#pragma unroll
    for (int fm = 0; fm < 4; ++fm)
#pragma unroll
      for (int fn = 0; fn < 4; ++fn)
        acc[fm][fn] = __builtin_amdgcn_mfma_f32_16x16x32_f16(af[fm], bf[fn], acc[fm][fn], 0, 0, 0);
    __syncthreads();
    cur = nxt;
  }

  // ---- fused epilogue ----
  const int col0 = bn + wn * 64;
  const int mode = col0 >> 10;
  const int h    = (col0 >> 6) & 15;

  if (mode <= 1) {
    f16* dst = mode ? kb : qb;
#pragma unroll
    for (int fm = 0; fm < 4; ++fm) {
#pragma unroll
      for (int r = 0; r < 4; ++r) {
        const int m = bm + wm * 64 + fm * 16 + quad * 4 + r;
        const int b = m >> 11, n = m & (N_TOK - 1);
        float ss = acc[fm][0][r] * acc[fm][0][r] + acc[fm][1][r] * acc[fm][1][r]
                 + acc[fm][2][r] * acc[fm][2][r] + acc[fm][3][r] * acc[fm][3][r];
        ss += __shfl_xor(ss, 1, 64);
        ss += __shfl_xor(ss, 2, 64);
        ss += __shfl_xor(ss, 4, 64);
        ss += __shfl_xor(ss, 8, 64);
        float sc2 = 1.0f / (sqrtf(ss) + 1e-8f);
        if (mode) sc2 *= 0.125f * LOG2E * score[n];
        f16* drow = dst + (((size_t)(b * H_DIM + h) * N_TOK + n) << 6);
#pragma unroll
        for (int fn = 0; fn < 4; ++fn)
          drow[fn * 16 + ln] = (f16)(acc[fm][fn][r] * sc2);
      }
    }
  } else {
    // V packing for K=32 PV: group32 = two fm's; half j<4 from fm=2F (r=j),
    // half j>=4 from fm=2F+1 (r=j-4). col = dblk*16+ln.
    const int m0  = bm + wm * 64;
    const int b   = m0 >> 11;
    const int tg0 = (m0 & (N_TOK - 1)) >> 5;      // 32-token group index
    f16* vb = vfrag + (((size_t)(b * H_DIM + h) * 64 + tg0) * 4) * 512 + lane * 8;
#pragma unroll
    for (int F = 0; F < 2; ++F)
#pragma unroll
      for (int dblk = 0; dblk < 4; ++dblk) {
        f16x8 v8;
#pragma unroll
        for (int r = 0; r < 4; ++r) v8[r]     = (f16)acc[2 * F][dblk][r];
#pragma unroll
        for (int r = 0; r < 4; ++r) v8[4 + r] = (f16)acc[2 * F + 1][dblk][r];
        *(f16x8*)(vb + ((size_t)F * 4 + dblk) * 512) = v8;
      }
  }
}

// ---------------------------------------------------------------------------
// Proj GEMM (unchanged): 128x64 tile, 4 waves (4x1), acc[2][4]. Grid (16,32)
// = 512 blocks = 2/CU. XCD-swizzled. 24KB LDS, 2-phase BK=32 schedule.
// ---------------------------------------------------------------------------
__global__ __launch_bounds__(256) void gemm_proj(const f16* __restrict__ A,
                                                 const f16* __restrict__ B,
                                                 const float* __restrict__ bias,
                                                 float* __restrict__ out) {
  __shared__ __align__(16) struct { f16 As[2 * SUB]; f16 Bs[2 * SUBB]; } sm;
  f32x4 acc[2][4];
#pragma unroll
  for (int i = 0; i < 2; ++i)
#pragma unroll
    for (int j = 0; j < 4; ++j) acc[i][j] = (f32x4){0.f, 0.f, 0.f, 0.f};

  // XCD swizzle: grid (16,32), nwg=512 (512%8==0 -> bijective).
  const int ld  = blockIdx.y * 16 + blockIdx.x;
  const int xcd = ld & 7, idx = ld >> 3;          // idx 0..63
  const int byn = xcd * 4 + idx / 16;             // 0..31
  const int bxn = idx % 16;                       // 0..15
  const int bm = byn * 128, bn = bxn * 64;

  const int tid  = threadIdx.x;
  const int w    = tid >> 6, lane = tid & 63;
  const int ln   = lane & 15, quad = lane >> 4;
  const int sr   = lane >> 2;
  const int sc   = (((lane & 3) ^ ((lane >> 4) & 3)) << 3);
  const int ro   = ((quad ^ ((ln >> 2) & 3)) << 3);

  const f16* Ag0 = A + (size_t)(bm + w * 16 + sr) * C_DIM + sc;
  const f16* Ag1 = A + (size_t)(bm + (w + 4) * 16 + sr) * C_DIM + sc;
  const f16* Bg0 = B + (size_t)(bn + w * 16 + sr) * C_DIM + sc;
  f16* Al0 = sm.As + (w * 16) * 32;
  f16* Al1 = sm.As + ((w + 4) * 16) * 32;
  f16* Bl0 = sm.Bs + (w * 16) * 32;

  // ---- prologue ----
  gl_lds16(Ag0, Al0);
  gl_lds16(Ag1, Al1);
  gl_lds16(Bg0, Bl0);
  __syncthreads();

  int cur = 0;
  for (int k0 = 0; k0 < C_DIM; k0 += 32) {
    const int nxt = cur ^ 1;
    if (k0 + 32 < C_DIM) {
      gl_lds16(Ag0 + k0 + 32, Al0 + nxt * SUB);
      gl_lds16(Ag1 + k0 + 32, Al1 + nxt * SUB);
      gl_lds16(Bg0 + k0 + 32, Bl0 + nxt * SUBB);
    }
    const f16* Asub = sm.As + cur * SUB;
    const f16* Bsub = sm.Bs + cur * SUBB;
    f16x8 af[2], bf[4];
#pragma unroll
    for (int fm = 0; fm < 2; ++fm)
      af[fm] = *(const f16x8*)&Asub[(w * 32 + fm * 16 + ln) * 32 + ro];
#pragma unroll
    for (int fn = 0; fn < 4; ++fn)
      bf[fn] = *(const f16x8*)&Bsub[(fn * 16 + ln) * 32 + ro];
#pragma unroll
    for (int fm = 0; fm < 2; ++fm)
#pragma unroll
      for (int fn = 0; fn < 4; ++fn)
        acc[fm][fn] = __builtin_amdgcn_mfma_f32_16x16x32_f16(af[fm], bf[fn], acc[fm][fn], 0, 0, 0);
    __syncthreads();
    cur = nxt;
  }

  // ---- epilogue ----
  float bv[4];
#pragma unroll
  for (int fn = 0; fn < 4; ++fn) bv[fn] = bias[bn + fn * 16 + ln];
#pragma unroll
  for (int fm = 0; fm < 2; ++fm)
#pragma unroll
    for (int r = 0; r < 4; ++r) {
      const int m = bm + w * 32 + fm * 16 + quad * 4 + r;
#pragma unroll
      for (int fn = 0; fn < 4; ++fn)
        out[(size_t)m * C_DIM + bn + fn * 16 + ln] = acc[fm][fn][r] + bv[fn];
    }
}

// ---------------------------------------------------------------------------
// MFMA attention v13 (re-anchor run): v11 + K=32 PV. Per body: QK 8 + PV 8 +
// l 2 = 18 MFMA issues (was 28) at equal FLOPs. V pre-packed by gemm_qkv in
// matching slot order. Double-buffered LDS K/V with __syncthreads (compiler-
// placed waits — R12's manual vmcnt(1) choreography regressed, reverted).
// XOR swizzle, setprio, raw exp2 + packed f16 cvt softmax. 2 blocks/CU.
// ---------------------------------------------------------------------------
__global__ __launch_bounds__(512) void attn_mfma(const f16* __restrict__ qb,
                                                 const f16* __restrict__ kb,
                                                 const f16* __restrict__ vfrag,
                                                 const float* __restrict__ score,
                                                 const int* __restrict__ usem,
                                                 f16* __restrict__ obuf) {
  __shared__ __align__(16) f16 Kl[2][64][64];
  __shared__ __align__(16) f16 Vl[2][4096];

  const int tid  = threadIdx.x;
  const int w    = tid >> 6;           // 0..7
  const int lane = tid & 63;
  const int ln   = lane & 15;
  const int quad = lane >> 4;
  const int bh = blockIdx.x;                 // XCD-pinned: bh%8
  const int q0 = blockIdx.y * 128;
  const int b  = bh >> 4, h = bh & 15;
  const int umask = *usem;

  // Q B-frags: 16 q rows per wave (8 waves = 128 rows), in registers
  const f16* qp = qb + ((size_t)bh * N_TOK + q0 + w * 16 + ln) * HD + quad * 8;
  const f16x8 bq0 = *(const f16x8*)(qp);
  const f16x8 bq1 = *(const f16x8*)(qp + 32);
  const float sq = score[q0 + w * 16 + ln] - 0.1f;

  f32x4 O[4], Ol;
#pragma unroll
  for (int t = 0; t < 4; ++t) O[t] = (f32x4){0.f, 0.f, 0.f, 0.f};
  Ol = (f32x4){0.f, 0.f, 0.f, 0.f};
  const f16x8 ones8 = (f16x8){(f16)1.f, (f16)1.f, (f16)1.f, (f16)1.f,
                              (f16)1.f, (f16)1.f, (f16)1.f, (f16)1.f};

  const int sr  = tid >> 3;            // K stage row 0..63
  const int scc = (tid & 7) << 3;      // K stage col (halves, 16B per thread)
  const int sw  = (sr & 7) << 3;       // write-side swizzle (halves)
  const int wc0 = scc ^ sw;            // swizzled store col
  const int e3  = (ln & 7) << 3;       // read-side swizzle (halves)
  const int rc0 = (quad * 8) ^ e3;     // swizzled read cols
  const int rc1 = (32 + quad * 8) ^ e3;
  const int c0  = w;                   // V DMA chunk for this wave (1 of 8)
  const f16* kg = kb    + (size_t)bh * N_TOK * HD;
  const f16* vg = vfrag + (size_t)bh * 128 * 1024;

  // ---- prologue: stage tile 0 into buffer 0 ----
  gl_lds16(vg + c0 * 512 + lane * 8, &Vl[0][c0 * 512]);
  {
    const float4 k0r = *(const float4*)(kg + (size_t)sr * HD + scc);
    *(float4*)&Kl[0][sr][wc0] = k0r;
  }
  __syncthreads();

  auto body = [&](int k0, int cur, int nxt) {
    // ---- prefetch tile t+1: V via DMA into nxt, K into registers ----
    const int kn = (k0 + 64 < N_TOK) ? k0 + 64 : 0;
    const f16* vt = vg + (size_t)(kn >> 4) * 1024;
    gl_lds16(vt + c0 * 512 + lane * 8, &Vl[nxt][c0 * 512]);
    const float4 kn0 = *(const float4*)(kg + (size_t)(kn + sr) * HD + scc);

    // ---- S^T = K.Q^T from Kl[cur] (swizzled reads) ----
    f16x4 af[4];
    f32x4 c[4];
    __builtin_amdgcn_s_setprio(1);
#pragma unroll
    for (int t = 0; t < 4; ++t) {
      const f16x8 ka0 = *(const f16x8*)&Kl[cur][t * 16 + ln][rc0];
      const f16x8 ka1 = *(const f16x8*)&Kl[cur][t * 16 + ln][rc1];
      f32x4 cc = (f32x4){0.f, 0.f, 0.f, 0.f};
      cc = __builtin_amdgcn_mfma_f32_16x16x32_f16(ka0, bq0, cc, 0, 0, 0);
      cc = __builtin_amdgcn_mfma_f32_16x16x32_f16(ka1, bq1, cc, 0, 0, 0);
      c[t] = cc;
    }
    __builtin_amdgcn_s_setprio(0);

    // ---- softmax in-register (log2 domain; masked -> exp2(0)=1) ----
#pragma unroll
    for (int t = 0; t < 4; ++t) {
      const float4 sk = *(const float4*)&score[k0 + t * 16 + quad * 4];
      const float skr[4] = {sk.x, sk.y, sk.z, sk.w};
      float e[4];
#pragma unroll
      for (int r = 0; r < 4; ++r) {
        float x = c[t][r];
        if (umask && !(skr[r] > sq)) x = 0.f;
        e[r] = __builtin_amdgcn_exp2f(x);
      }
      union { fp16x2_b p[2]; f16x4 v; } u;
      u.p[0] = __builtin_amdgcn_cvt_pkrtz(e[0], e[1]);
      u.p[1] = __builtin_amdgcn_cvt_pkrtz(e[2], e[3]);
      af[t] = u.v;
    }

    // ---- O += P V at K=32: A = concat(af[2t],af[2t+1]); V pre-packed ----
    __builtin_amdgcn_s_setprio(1);
#pragma unroll
    for (int t32 = 0; t32 < 2; ++t32) {
      const f16x8 a8 = __builtin_shufflevector(af[2 * t32], af[2 * t32 + 1],
                                               0, 1, 2, 3, 4, 5, 6, 7);
      Ol = __builtin_amdgcn_mfma_f32_16x16x32_f16(a8, ones8, Ol, 0, 0, 0);
#pragma unroll
      for (int dblk = 0; dblk < 4; ++dblk) {
        const f16x8 vv = *(const f16x8*)&Vl[cur][(t32 * 4 + dblk) * 512 + lane * 8];
        O[dblk] = __builtin_amdgcn_mfma_f32_16x16x32_f16(a8, vv, O[dblk], 0, 0, 0);
      }
    }
    __builtin_amdgcn_s_setprio(0);

    // ---- stage prefetched K into Kl[nxt] (swizzled); barrier flips buffers --
    *(float4*)&Kl[nxt][sr][wc0] = kn0;
    __syncthreads();
  };

  for (int k0 = 0; k0 < N_TOK; k0 += 128) {
    body(k0, 0, 1);
    body(k0 + 64, 1, 0);
  }

  // ---- epilogue: l for q=quad*4+r sits in Ol[r] on every lane ----
#pragma unroll
  for (int r = 0; r < 4; ++r) {
    const float inv = 1.0f / Ol[r];
    const size_t row = (size_t)(b * N_TOK + q0 + w * 16 + quad * 4 + r);
#pragma unroll
    for (int t2 = 0; t2 < 4; ++t2)
      obuf[row * C_DIM + h * HD + t2 * 16 + ln] = (f16)(O[t2][r] * inv);
  }
}

// ---------------------------------------------------------------------------
extern "C" void kernel_launch(void* const* d_in, const int* in_sizes, int n_in,
                              void* d_out, int out_size, void* d_ws, size_t ws_size,
                              hipStream_t stream) {
  const float* x      = (const float*)d_in[0];
  const float* score  = (const float*)d_in[1];
  const float* qkv_w  = (const float*)d_in[2];
  const float* proj_w = (const float*)d_in[3];
  const float* proj_b = (const float*)d_in[4];
  const int*   usem   = (const int*)d_in[5];
  float* out = (float*)d_out;

  f16* xh    = (f16*)d_ws;
  f16* wh    = xh  + (size_t)M_TOK * C_DIM;
  f16* pwh   = wh  + (size_t)3 * C_DIM * C_DIM;
  f16* qb    = pwh + (size_t)C_DIM * C_DIM;
  f16* kb    = qb  + (size_t)M_TOK * C_DIM;
  f16* vfrag = kb  + (size_t)M_TOK * C_DIM;
  f16* obuf  = vfrag + (size_t)M_TOK * C_DIM;

  cvt_all<<<(CVT_X4 + CVT_W4 + CVT_P4) / 256, 256, 0, stream>>>(x, qkv_w, proj_w, xh, wh, pwh);
  {
    dim3 grid(3 * C_DIM / 128, M_TOK / 256);   // 24 x 16 = 384 blocks, 512 thr
    gemm_qkv<<<grid, 512, 0, stream>>>(xh, wh, score, qb, kb, vfrag);
  }
  {
    dim3 grid(2 * H_DIM, N_TOK / 128);   // bh fastest -> XCD-pinned K/V
    attn_mfma<<<grid, 512, 0, stream>>>(qb, kb, vfrag, score, usem, obuf);
  }
  {
    dim3 grid(C_DIM / 64, M_TOK / 128);  // 512 blocks = 2/CU
    gemm_proj<<<grid, 256, 0, stream>>>(obuf, pwh, proj_b, out);
  }
}